// Round 17
// baseline (412.151 us; speedup 1.0000x reference)
//
#include <hip/hip_runtime.h>
#include <stdint.h>

// ============================================================================
// Fused MHA w/ RoPE, MI355X bf16-MFMA implementation.  FINAL (R16).
// = R15 with s_setprio removed from the GEMM MFMA phase (T5 is
// structure-conditional: measured NEGATIVE on lockstep barrier-synced GEMMs
// (m190), positive only on role-split 8-phase schedules; kept in attn where
// +4-7 is measured (m191)).
// GEMM: R6 schedule (4 phases/K-tile, 1 barrier/phase, spread staging
// 1 unit/phase in consumption order, vmcnt(4) deadlines, conflict-free
// swizzles ^((row&7)<<4) / ^((row&6)<<3), XCD band map). Attn = R2 structure
// (QBLK=128, swapped QK^T in-lane softmax, dbuf K/V, counted vmcnt, LPT).
// Schedule search closed: R4/R7/R8/R10/R12 variants all lost to this one.
// ============================================================================

using u16 = unsigned short;
typedef __bf16 bf16_t;
typedef __bf16 bf16x8 __attribute__((ext_vector_type(8)));
typedef float  f32x4  __attribute__((ext_vector_type(4)));
typedef u16    u16x4  __attribute__((ext_vector_type(4)));

#define DEVI static __device__ __forceinline__
#define AS1 __attribute__((address_space(1)))
#define AS3 __attribute__((address_space(3)))
#define GLL16(g,l) __builtin_amdgcn_global_load_lds((const AS1 void*)(g), (AS3 void*)(l), 16, 0, 0)

DEVI u16 f2bf(float x){ bf16_t h=(bf16_t)x; return __builtin_bit_cast(u16,h); }
DEVI f32x4 mfma16(bf16x8 a, bf16x8 b, f32x4 c){
  return __builtin_amdgcn_mfma_f32_16x16x32_bf16(a,b,c,0,0,0);
}

// ---------------------------------------------------------------- prep
// Grid-stride (2048 blocks x 256 thr): x-convert (4.19M float4), weight
// converts (4 x 1.05M float4, contiguous dest), RoPE cos/sin table.
__global__ __launch_bounds__(256) void k_prep(
    const float* __restrict__ x,
    const float* __restrict__ w0, const float* __restrict__ w1,
    const float* __restrict__ w2, const float* __restrict__ w3,
    const int* __restrict__ pos,
    u16* __restrict__ xb, u16* __restrict__ wb,
    float* __restrict__ ct, float* __restrict__ stab){
  const int gt = blockIdx.x*256 + threadIdx.x;     // 0..524287
  // x: 16.7M floats = 4,194,304 float4 chunks (8 iters/thread)
  for (int i = gt; i < 4194304; i += 524288){
    float4 v = ((const float4*)x)[i];
    u16x4 o = { f2bf(v.x), f2bf(v.y), f2bf(v.z), f2bf(v.w) };
    ((u16x4*)xb)[i] = o;
  }
  // weights: 4 x 1,048,576 float4 chunks (8 iters/thread)
  for (int i = gt; i < 4194304; i += 524288){
    const int seg = i >> 20;
    const float* w = (seg==0)? w0 : (seg==1)? w1 : (seg==2)? w2 : w3;
    const int li = i & 1048575;
    float4 v = ((const float4*)w)[li];
    u16x4 o = { f2bf(v.x), f2bf(v.y), f2bf(v.z), f2bf(v.w) };
    ((u16x4*)(wb + (size_t)seg*4194304))[li] = o;
  }
  // RoPE table: 131072 entries (first 131072 threads, 1 iter)
  for (int i = gt; i < 131072; i += 524288){
    int s = i>>6, f = i&63;
    float inv = __expf(-0.14391275442161033f * (float)f);  // 10000^(-f/64)
    float a = (float)pos[s] * inv;
    float sv, cv; sincosf(a, &sv, &cv);
    ct[i] = cv; stab[i] = sv;
  }
}

// ---------------------------------------------------------------- GEMM
// C[M=8192][N] = A[M][K=2048] * Bt[N][K]^T, bf16 in.
// 256x256 tile, BK=64, 8 waves (2Mx4N), per-wave 128x64 out = acc[2][4][4].
// LDS: A [2buf][256 rows][128B] read-swz ^((row&7)<<4)  (2-way, free);
//      B [2buf][2 kk][256 rows][64B] read-swz ^((row&6)<<3) (2-way, free).
// 4 phases/K-tile, 1 barrier each. Stage order = consume order:
//   ph0: A-mh0 (2 GLL)  ph1: B-kk0  ph2: A-mh1  ph3: B-kk1
// vmcnt(4) in ph0/ph1/ph3 bodies. No drain in main loop.
// EPI==4: N=6144 fused QKV (seg0 Q-RoPE, seg1 K-RoPE, seg2 V-transpose).
// EPI==3: N=2048, f32 row-major out.
template<int EPI>
__global__ __launch_bounds__(512,2) void k_gemm(
    const bf16_t* __restrict__ A, const bf16_t* __restrict__ Bt,
    void* __restrict__ O0, void* __restrict__ O1, void* __restrict__ O2,
    const float* __restrict__ ct, const float* __restrict__ stab)
{
  __shared__ char Al[2][32768];
  __shared__ char Bl[2][2][16384];
  const int tid = threadIdx.x, wave = tid>>6, lane = tid&63;
  const int rgrp = lane>>4, cidx = lane&15;
  const int wm = wave>>2, wn = wave&3;
  // XCD band mapping: xcd owns M-blocks [xcd*4,+4), walks M-fast, N-outer.
  const int xcd = blockIdx.x & 7, ii = blockIdx.x >> 3;
  const int by = xcd*4 + (ii&3), bx = ii>>2;
  const int bm = by*256, bn = bx*256;

  const char* Ag = (const char*)A  + (size_t)bm*4096;
  const char* Bg = (const char*)Bt + (size_t)bn*4096;

  // staging source precompute (inverse swizzle per rule 21)
  const int a_r  = lane>>3;                               // 0..7
  const int a_src = ((lane&7)*16) ^ ((a_r&7)<<4);         // within 128B row
  const int b_r  = lane>>2;                               // 0..15
  const int b_src = ((lane&3)*16) ^ ((b_r&6)<<3);         // within 64B kk-half
  // read-side swizzles (row&7 == cidx&7, row&6 == cidx&6: rows = mult16+cidx)
  const int aswz = (cidx&7)<<4;
  const int bswz = (cidx&6)<<3;

  f32x4 acc[2][4][4] = {};
  bf16x8 af[4], bfA[4], bfB[4];

#define STAGE_A(b, kt_, mh) do{ _Pragma("unroll") \
  for (int c_=0;c_<2;++c_){ \
    const int r0_ = c_*128 + (mh)*64 + wave*8; \
    GLL16(Ag + (size_t)(r0_ + a_r)*4096 + (size_t)(kt_)*128 + a_src, \
          &Al[b][r0_*128]); } }while(0)
#define STAGE_B(b, kt_, kk) do{ _Pragma("unroll") \
  for (int c_=0;c_<2;++c_){ \
    const int r0_ = c_*128 + wave*16; \
    GLL16(Bg + (size_t)(r0_ + b_r)*4096 + (size_t)(kt_)*128 + (kk)*64 + b_src, \
          &Bl[b][kk][r0_*64]); } }while(0)
#define LOAD_AF(MH, KK) do{ _Pragma("unroll") \
  for (int fi=0; fi<4; ++fi) \
    af[fi] = *(const bf16x8*)&Al[cur][(wm*128 + (MH)*64 + fi*16 + cidx)*128 \
                                      + (((KK)*64 + rgrp*16) ^ aswz)]; }while(0)
#define LOAD_BF(DST, KK) do{ _Pragma("unroll") \
  for (int fj=0; fj<4; ++fj) \
    DST[fj] = *(const bf16x8*)&Bl[cur][KK][(wn*64 + fj*16 + cidx)*64 \
                                      + ((rgrp*16) ^ bswz)]; }while(0)
#define PHASE_MFMA(ACCI, BFR) do{ \
  __builtin_amdgcn_s_barrier(); \
  _Pragma("unroll") for (int fi=0; fi<4; ++fi){ \
    _Pragma("unroll") for (int fj=0; fj<4; ++fj){ \
      acc[ACCI][fi][fj] = mfma16(af[fi], BFR[fj], acc[ACCI][fi][fj]); }} }while(0)
#define VMC(n) asm volatile("s_waitcnt vmcnt(" #n ")" ::: "memory")

  // prologue: tile 0's 4 units in consumption order; allow 2 newest pending.
  STAGE_A(0, 0, 0); STAGE_B(0, 0, 0); STAGE_A(0, 0, 1); STAGE_B(0, 0, 1);
  VMC(4);
  __builtin_amdgcn_s_barrier();
  int cur = 0;
  for (int t=0; t<32; ++t){
    const bool pf = (t < 31);
    // ---- ph0: (mh0,kk0); stage A-mh0(t+1)
    LOAD_AF(0,0); LOAD_BF(bfA, 0);
    if (pf){ STAGE_A(cur^1, t+1, 0); VMC(4); } else VMC(2);
    PHASE_MFMA(0, bfA);
    // ---- ph1: (mh1,kk0); stage B-kk0(t+1)
    LOAD_AF(1,0);
    if (pf){ STAGE_B(cur^1, t+1, 0); VMC(4); } else VMC(0);
    PHASE_MFMA(1, bfA);
    // ---- ph2: (mh0,kk1); stage A-mh1(t+1)  [no vmcnt point]
    LOAD_AF(0,1); LOAD_BF(bfB, 1);
    if (pf) STAGE_A(cur^1, t+1, 1);
    PHASE_MFMA(0, bfB);
    // ---- ph3: (mh1,kk1); stage B-kk1(t+1)
    LOAD_AF(1,1);
    if (pf){ STAGE_B(cur^1, t+1, 1); VMC(4); }
    PHASE_MFMA(1, bfB);
    cur ^= 1;
  }
#undef STAGE_A
#undef STAGE_B
#undef LOAD_AF
#undef LOAD_BF
#undef PHASE_MFMA
#undef VMC

  if constexpr (EPI==3){
    float* O = (float*)O0;
    #pragma unroll
    for (int mh=0; mh<2; ++mh)
      #pragma unroll
      for (int fi=0; fi<4; ++fi){
        const int m0 = bm + wm*128 + mh*64 + fi*16 + rgrp*4;
        #pragma unroll
        for (int fj=0; fj<4; ++fj){
          const int n = bn + wn*64 + fj*16 + cidx;
          #pragma unroll
          for (int r=0; r<4; ++r)
            O[(size_t)(m0+r)*2048 + n] = acc[mh][fi][fj][r];
        }
      }
  } else {
    const int seg = bn>>11;                  // block-uniform: 0=Q, 1=K, 2=V
    if (seg==2){
      u16* O = (u16*)O2;                     // v_t [bh][128][2048]
      #pragma unroll
      for (int mh=0; mh<2; ++mh)
        #pragma unroll
        for (int fi=0; fi<4; ++fi){
          const int m0 = bm + wm*128 + mh*64 + fi*16 + rgrp*4;
          const int b = m0>>11, s0 = m0&2047;
          #pragma unroll
          for (int fj=0; fj<4; ++fj){
            const int nl = (bn + wn*64 + fj*16 + cidx) & 2047;
            const int h = nl>>7, d = nl&127;
            u16x4 pk = { f2bf(acc[mh][fi][fj][0]), f2bf(acc[mh][fi][fj][1]),
                         f2bf(acc[mh][fi][fj][2]), f2bf(acc[mh][fi][fj][3]) };
            *(u16x4*)(O + ((size_t)((b*16+h)*128 + d)*2048 + s0)) = pk;
          }
        }
    } else {
      u16* O = seg ? (u16*)O1 : (u16*)O0;    // [bh][2048][128]
      const float qs = seg ? 1.0f : 0.08838834764831845f;  // 1/sqrt(128) on Q
      #pragma unroll
      for (int fj=0; fj<4; ++fj){
        const int nl = (bn + wn*64 + fj*16 + cidx) & 2047;
        const int h = nl>>7, d = nl&127, f = (nl&127)>>1;
        #pragma unroll
        for (int mh=0; mh<2; ++mh)
          #pragma unroll
          for (int fi=0; fi<4; ++fi){
            #pragma unroll
            for (int r=0; r<4; ++r){
              const int m = bm + wm*128 + mh*64 + fi*16 + rgrp*4 + r;
              const int b = m>>11, s = m&2047;
              float v = acc[mh][fi][fj][r];
              float p = __shfl_xor(v, 1, 64);  // RoPE partner: d^1 lives in lane^1
              float cv = ct[s*64+f], sv = stab[s*64+f];
              float o = (d&1) ? (p*sv + v*cv) : (v*cv - p*sv);
              o *= qs;
              O[(size_t)(b*16+h)*262144 + (size_t)s*128 + d] = f2bf(o);
            }
          }
      }
    }
  }
}

// ---------------------------------------------------------------- flash attn
// 1-D grid, 1024 blocks, LPT order: qt = 15 - bid/64, bh = bid%64.
// QBLK=128: wave w owns q rows [qt*128 + w*32, +32) = 2 M-fragments.
// Swapped QK^T: stt[m][t] = mfma(K_frag, Q_frag) -> S[key][q], q = lane&15.
// Softmax: in-lane 16-value reduce + shfl_xor(16,32). P packed as u16x4 ->
// 8 ds_write_b64/wave. K/V double-buffered, XOR-swizzled (rule 21), counted
// vmcnt(8) + raw s_barrier (T3/T4), setprio (T5, attn-positive), defer-max.
__global__ __launch_bounds__(256,2) void k_attn(
  const bf16_t* __restrict__ Q, const bf16_t* __restrict__ K,
  const bf16_t* __restrict__ Vt, u16* __restrict__ Mg)
{
  __shared__ char kl[2][16384];
  __shared__ char vl[2][16384];
  __shared__ char pl[4][4096];                // per-wave P: 32 q-rows x 128B, XOR-swz
  const int tid=threadIdx.x, wave=tid>>6, lane=tid&63;
  const int rgrp=lane>>4, cidx=lane&15;
  const int bid=blockIdx.x;
  const int qt = 15 - (bid>>6);
  const int bh = bid & 63;
  const int qbase = qt*128;
  const int last = 2*qt + 1;                  // inclusive last k-tile

  bf16x8 qf[2][4];                            // B-operand: lane <- q row m*16+cidx
  #pragma unroll
  for (int m=0;m<2;++m){
    const bf16_t* qp = Q + ((size_t)bh*2048 + qbase + wave*32 + m*16 + cidx)*128 + rgrp*8;
    #pragma unroll
    for (int ds=0; ds<4; ++ds) qf[m][ds] = *(const bf16x8*)(qp + ds*32);
  }
  f32x4 oacc[2][8] = {};
  float mrow[2] = {-1e30f,-1e30f};
  float lrow[2] = {0.f,0.f};

  const char* Kg = (const char*)K  + (size_t)bh*524288;
  const char* Vg = (const char*)Vt + (size_t)bh*524288;
  char* pw = pl[wave];
  const int L0 = tid*16;
  const int qrow0 = qbase + wave*32 + cidx;   // q-row of frag m: qrow0 + m*16

  #define STAGE(buf, kt_) do{                                                  \
    _Pragma("unroll")                                                          \
    for (int i_=0;i_<4;++i_){                                                  \
      int L_ = i_*4096 + L0;                                                   \
      int row_ = L_>>8;                                                        \
      int in_ = (L_&255) ^ ((row_&7)<<4);                                      \
      GLL16(Kg + (size_t)((kt_)*64+row_)*256 + in_, &kl[buf][i_*4096 + wave*1024]); \
    }                                                                          \
    _Pragma("unroll")                                                          \
    for (int i_=0;i_<4;++i_){                                                  \
      int L_ = i_*4096 + L0;                                                   \
      int d_ = L_>>7;                                                          \
      int in_ = (L_&127) ^ ((d_&7)<<4);                                        \
      GLL16(Vg + (size_t)d_*4096 + (kt_)*128 + in_, &vl[buf][i_*4096 + wave*1024]); \
    }                                                                          \
  }while(0)

  STAGE(0, 0);
  int cur = 0;
  for (int kt=0; kt<=last; ++kt){
    const bool pf = (kt < last);
    if (pf) STAGE(cur^1, kt+1);               // 8 more GLLs in flight
    if (pf) asm volatile("s_waitcnt vmcnt(8)" ::: "memory");
    else    asm volatile("s_waitcnt vmcnt(0)" ::: "memory");
    __builtin_amdgcn_s_barrier();             // buf[cur] ready everywhere

    // ---- S^T = K Q^T : stt[m][t][r] = S[key = kt*64+t*16+rgrp*4+r][q = qrow0+m*16]
    f32x4 stt[2][4];
    #pragma unroll
    for (int m=0;m<2;++m)
      #pragma unroll
      for (int t=0;t<4;++t) stt[m][t] = (f32x4){0.f,0.f,0.f,0.f};
    __builtin_amdgcn_s_setprio(1);
    #pragma unroll
    for (int t=0;t<4;++t){
      const int krow = t*16 + cidx;           // A-operand: lane <- K row krow
      #pragma unroll
      for (int ds=0; ds<4; ++ds){
        const int off = (krow*256 + ds*64 + rgrp*16) ^ ((krow&7)<<4);
        bf16x8 kf = *(const bf16x8*)(&kl[cur][off]);
        stt[0][t] = mfma16(kf, qf[0][ds], stt[0][t]);
        stt[1][t] = mfma16(kf, qf[1][ds], stt[1][t]);
      }
    }
    __builtin_amdgcn_s_setprio(0);

    // ---- causal mask (only the last two tiles of this q-block can clip)
    if (kt >= 2*qt){
      #pragma unroll
      for (int m=0;m<2;++m){
        const int q = qrow0 + m*16;
        #pragma unroll
        for (int t=0;t<4;++t){
          #pragma unroll
          for (int r=0;r<4;++r){
            const int key = kt*64 + t*16 + rgrp*4 + r;
            if (key > q) stt[m][t][r] = -1e30f;
          }
        }
      }
    }

    // ---- online softmax, in-lane per q-row
    #pragma unroll
    for (int m=0;m<2;++m){
      float vm = stt[m][0][0];
      #pragma unroll
      for (int t=0;t<4;++t)
        #pragma unroll
        for (int r=0;r<4;++r) vm = fmaxf(vm, stt[m][t][r]);
      vm = fmaxf(vm, __shfl_xor(vm, 16, 64));
      vm = fmaxf(vm, __shfl_xor(vm, 32, 64));
      if (!__all(vm <= mrow[m] + 8.f)){       // T13: rescale only on real growth
        float mn = fmaxf(mrow[m], vm);
        float c = __expf(mrow[m]-mn);
        mrow[m]=mn; lrow[m]*=c;
        float cr0 = __shfl(c, rgrp*4+0, 64), cr1 = __shfl(c, rgrp*4+1, 64);
        float cr2 = __shfl(c, rgrp*4+2, 64), cr3 = __shfl(c, rgrp*4+3, 64);
        #pragma unroll
        for (int d=0;d<8;++d){
          oacc[m][d][0]*=cr0; oacc[m][d][1]*=cr1;
          oacc[m][d][2]*=cr2; oacc[m][d][3]*=cr3;
        }
      }
      float lt = 0.f;
      #pragma unroll
      for (int t=0;t<4;++t)
        #pragma unroll
        for (int r=0;r<4;++r){
          float p = __expf(stt[m][t][r]-mrow[m]);
          stt[m][t][r]=p; lt+=p;
        }
      lt += __shfl_xor(lt, 16, 64);
      lt += __shfl_xor(lt, 32, 64);
      lrow[m] += lt;
    }

    // ---- P pack -> per-wave LDS (XOR-swz), 4 consecutive keys per write
    #pragma unroll
    for (int m=0;m<2;++m){
      const int prow = m*16 + cidx;
      char* base = pw + prow*128;
      const int swz = (prow&7)<<4;
      #pragma unroll
      for (int t=0;t<4;++t){
        u16x4 pk = { f2bf(stt[m][t][0]), f2bf(stt[m][t][1]), f2bf(stt[m][t][2]), f2bf(stt[m][t][3]) };
        *(u16x4*)(base + ((t*32 + rgrp*8) ^ swz)) = pk;
      }
    }
    asm volatile("s_waitcnt lgkmcnt(0)" ::: "memory");
    __builtin_amdgcn_sched_barrier(0);

    // ---- O += P V^T
    __builtin_amdgcn_s_setprio(1);
    #pragma unroll
    for (int ks=0; ks<2; ++ks){
      const int swzc = (cidx&7)<<4;
      bf16x8 pa0 = *(const bf16x8*)(pw + (     cidx)*128 + ((ks*64 + rgrp*16) ^ swzc));
      bf16x8 pa1 = *(const bf16x8*)(pw + (16 + cidx)*128 + ((ks*64 + rgrp*16) ^ swzc));
      #pragma unroll
      for (int dsub=0; dsub<8; ++dsub){
        const int d = dsub*16 + cidx;
        const int off = (d*128 + ks*64 + rgrp*16) ^ ((d&7)<<4);
        bf16x8 vf = *(const bf16x8*)(&vl[cur][off]);
        oacc[0][dsub] = mfma16(pa0, vf, oacc[0][dsub]);
        oacc[1][dsub] = mfma16(pa1, vf, oacc[1][dsub]);
      }
    }
    __builtin_amdgcn_s_setprio(0);
    __builtin_amdgcn_s_barrier();             // all reads of buf[cur] done
    cur ^= 1;
  }
  #undef STAGE

  const int b = bh>>4, h = bh&15;
  #pragma unroll
  for (int m=0;m<2;++m){
    float linv = 1.f/lrow[m];
    float ir[4];
    #pragma unroll
    for (int r=0;r<4;++r) ir[r] = __shfl(linv, rgrp*4+r, 64);
    #pragma unroll
    for (int dsub=0;dsub<8;++dsub){
      const int col = h*128 + dsub*16 + cidx;
      #pragma unroll
      for (int r=0;r<4;++r){
        const int srow = qbase + wave*32 + m*16 + rgrp*4 + r;
        Mg[((size_t)b*2048 + srow)*2048 + col] = f2bf(oacc[m][dsub][r]*ir[r]);
      }
    }
  }
}

// ---------------------------------------------------------------- launch
extern "C" void kernel_launch(void* const* d_in, const int* in_sizes, int n_in,
                              void* d_out, int out_size, void* d_ws, size_t ws_size,
                              hipStream_t stream)
{
  (void)in_sizes; (void)n_in; (void)out_size; (void)ws_size;
  const float* x  = (const float*)d_in[0];
  const int*   tp = (const int*)d_in[1];
  const float* Wq = (const float*)d_in[2];
  const float* Wk = (const float*)d_in[3];
  const float* Wv = (const float*)d_in[4];
  const float* Wo = (const float*)d_in[5];

  char* ws = (char*)d_ws;
  bf16_t* xb  = (bf16_t*)(ws);                 // 33.5MB, reused as merged later
  bf16_t* wqb = (bf16_t*)(ws + 33554432);      // wq|wk|wv|wo contiguous
  bf16_t* wob = (bf16_t*)(ws + 58720256);
  bf16_t* vt  = (bf16_t*)(ws + 67108864);      // 33.5MB
  float*  ct  = (float*) (ws + 100663296);     // 512KB
  float*  stb = (float*) (ws + 101187584);     // 512KB  (end ~97MB)
  bf16_t* qr  = (bf16_t*)d_out;                // q_rope in d_out (dead before final GEMM)
  bf16_t* kr  = (bf16_t*)((char*)d_out + 33554432);
  bf16_t* mg  = xb;                            // merged reuses xb

  k_prep<<<2048,256,0,stream>>>(x, Wq, Wk, Wv, Wo, tp,
                                (u16*)xb, (u16*)wqb, ct, stb);

  k_gemm<4><<<768,512,0,stream>>>(xb, wqb, qr, kr, vt, ct, stb);
  k_attn<<<1024,256,0,stream>>>(qr, kr, vt, (u16*)mg);
  k_gemm<3><<<256,512,0,stream>>>(mg, wob, d_out, nullptr, nullptr, nullptr, nullptr);
}

// Round 18
// 387.571 us; speedup vs baseline: 1.0634x; 1.0634x over previous
//
#include <hip/hip_runtime.h>
#include <stdint.h>

// ============================================================================
// Fused MHA w/ RoPE, MI355X bf16-MFMA implementation.  FINAL (R17 = R15).
// R16 post-mortem: removing s_setprio from the GEMM MFMA phase LOST 27 µs
// (MfmaUtil 43.5->37.0) — with 2 blocks/CU co-resident the waves have role
// diversity (T5's prerequisite), so setprio pays here. Restored.
// GEMM: R6 schedule (4 phases/K-tile, 1 barrier/phase, spread staging
// 1 unit/phase in consumption order, vmcnt(4) deadlines, conflict-free
// swizzles ^((row&7)<<4) / ^((row&6)<<3), XCD band map). Attn = R2 structure
// (QBLK=128, swapped QK^T in-lane softmax, dbuf K/V, counted vmcnt, LPT).
// Schedule search closed: R4/R7/R8/R10/R12/R16 variants all lost to this.
// ============================================================================

using u16 = unsigned short;
typedef __bf16 bf16_t;
typedef __bf16 bf16x8 __attribute__((ext_vector_type(8)));
typedef float  f32x4  __attribute__((ext_vector_type(4)));
typedef u16    u16x4  __attribute__((ext_vector_type(4)));

#define DEVI static __device__ __forceinline__
#define AS1 __attribute__((address_space(1)))
#define AS3 __attribute__((address_space(3)))
#define GLL16(g,l) __builtin_amdgcn_global_load_lds((const AS1 void*)(g), (AS3 void*)(l), 16, 0, 0)

DEVI u16 f2bf(float x){ bf16_t h=(bf16_t)x; return __builtin_bit_cast(u16,h); }
DEVI f32x4 mfma16(bf16x8 a, bf16x8 b, f32x4 c){
  return __builtin_amdgcn_mfma_f32_16x16x32_bf16(a,b,c,0,0,0);
}

// ---------------------------------------------------------------- prep
// Grid-stride (2048 blocks x 256 thr): x-convert (4.19M float4), weight
// converts (4 x 1.05M float4, contiguous dest), RoPE cos/sin table.
__global__ __launch_bounds__(256) void k_prep(
    const float* __restrict__ x,
    const float* __restrict__ w0, const float* __restrict__ w1,
    const float* __restrict__ w2, const float* __restrict__ w3,
    const int* __restrict__ pos,
    u16* __restrict__ xb, u16* __restrict__ wb,
    float* __restrict__ ct, float* __restrict__ stab){
  const int gt = blockIdx.x*256 + threadIdx.x;     // 0..524287
  // x: 16.7M floats = 4,194,304 float4 chunks (8 iters/thread)
  for (int i = gt; i < 4194304; i += 524288){
    float4 v = ((const float4*)x)[i];
    u16x4 o = { f2bf(v.x), f2bf(v.y), f2bf(v.z), f2bf(v.w) };
    ((u16x4*)xb)[i] = o;
  }
  // weights: 4 x 1,048,576 float4 chunks (8 iters/thread)
  for (int i = gt; i < 4194304; i += 524288){
    const int seg = i >> 20;
    const float* w = (seg==0)? w0 : (seg==1)? w1 : (seg==2)? w2 : w3;
    const int li = i & 1048575;
    float4 v = ((const float4*)w)[li];
    u16x4 o = { f2bf(v.x), f2bf(v.y), f2bf(v.z), f2bf(v.w) };
    ((u16x4*)(wb + (size_t)seg*4194304))[li] = o;
  }
  // RoPE table: 131072 entries (first 131072 threads, 1 iter)
  for (int i = gt; i < 131072; i += 524288){
    int s = i>>6, f = i&63;
    float inv = __expf(-0.14391275442161033f * (float)f);  // 10000^(-f/64)
    float a = (float)pos[s] * inv;
    float sv, cv; sincosf(a, &sv, &cv);
    ct[i] = cv; stab[i] = sv;
  }
}

// ---------------------------------------------------------------- GEMM
// C[M=8192][N] = A[M][K=2048] * Bt[N][K]^T, bf16 in.
// 256x256 tile, BK=64, 8 waves (2Mx4N), per-wave 128x64 out = acc[2][4][4].
// LDS: A [2buf][256 rows][128B] read-swz ^((row&7)<<4)  (2-way, free);
//      B [2buf][2 kk][256 rows][64B] read-swz ^((row&6)<<3) (2-way, free).
// 4 phases/K-tile, 1 barrier each. Stage order = consume order:
//   ph0: A-mh0 (2 GLL)  ph1: B-kk0  ph2: A-mh1  ph3: B-kk1
// vmcnt(4) in ph0/ph1/ph3 bodies. No drain in main loop.
// EPI==4: N=6144 fused QKV (seg0 Q-RoPE, seg1 K-RoPE, seg2 V-transpose).
// EPI==3: N=2048, f32 row-major out.
template<int EPI>
__global__ __launch_bounds__(512,2) void k_gemm(
    const bf16_t* __restrict__ A, const bf16_t* __restrict__ Bt,
    void* __restrict__ O0, void* __restrict__ O1, void* __restrict__ O2,
    const float* __restrict__ ct, const float* __restrict__ stab)
{
  __shared__ char Al[2][32768];
  __shared__ char Bl[2][2][16384];
  const int tid = threadIdx.x, wave = tid>>6, lane = tid&63;
  const int rgrp = lane>>4, cidx = lane&15;
  const int wm = wave>>2, wn = wave&3;
  // XCD band mapping: xcd owns M-blocks [xcd*4,+4), walks M-fast, N-outer.
  const int xcd = blockIdx.x & 7, ii = blockIdx.x >> 3;
  const int by = xcd*4 + (ii&3), bx = ii>>2;
  const int bm = by*256, bn = bx*256;

  const char* Ag = (const char*)A  + (size_t)bm*4096;
  const char* Bg = (const char*)Bt + (size_t)bn*4096;

  // staging source precompute (inverse swizzle per rule 21)
  const int a_r  = lane>>3;                               // 0..7
  const int a_src = ((lane&7)*16) ^ ((a_r&7)<<4);         // within 128B row
  const int b_r  = lane>>2;                               // 0..15
  const int b_src = ((lane&3)*16) ^ ((b_r&6)<<3);         // within 64B kk-half
  // read-side swizzles (row&7 == cidx&7, row&6 == cidx&6: rows = mult16+cidx)
  const int aswz = (cidx&7)<<4;
  const int bswz = (cidx&6)<<3;

  f32x4 acc[2][4][4] = {};
  bf16x8 af[4], bfA[4], bfB[4];

#define STAGE_A(b, kt_, mh) do{ _Pragma("unroll") \
  for (int c_=0;c_<2;++c_){ \
    const int r0_ = c_*128 + (mh)*64 + wave*8; \
    GLL16(Ag + (size_t)(r0_ + a_r)*4096 + (size_t)(kt_)*128 + a_src, \
          &Al[b][r0_*128]); } }while(0)
#define STAGE_B(b, kt_, kk) do{ _Pragma("unroll") \
  for (int c_=0;c_<2;++c_){ \
    const int r0_ = c_*128 + wave*16; \
    GLL16(Bg + (size_t)(r0_ + b_r)*4096 + (size_t)(kt_)*128 + (kk)*64 + b_src, \
          &Bl[b][kk][r0_*64]); } }while(0)
#define LOAD_AF(MH, KK) do{ _Pragma("unroll") \
  for (int fi=0; fi<4; ++fi) \
    af[fi] = *(const bf16x8*)&Al[cur][(wm*128 + (MH)*64 + fi*16 + cidx)*128 \
                                      + (((KK)*64 + rgrp*16) ^ aswz)]; }while(0)
#define LOAD_BF(DST, KK) do{ _Pragma("unroll") \
  for (int fj=0; fj<4; ++fj) \
    DST[fj] = *(const bf16x8*)&Bl[cur][KK][(wn*64 + fj*16 + cidx)*64 \
                                      + ((rgrp*16) ^ bswz)]; }while(0)
#define PHASE_MFMA(ACCI, BFR) do{ \
  __builtin_amdgcn_s_barrier(); \
  __builtin_amdgcn_s_setprio(1); \
  _Pragma("unroll") for (int fi=0; fi<4; ++fi){ \
    _Pragma("unroll") for (int fj=0; fj<4; ++fj){ \
      acc[ACCI][fi][fj] = mfma16(af[fi], BFR[fj], acc[ACCI][fi][fj]); }} \
  __builtin_amdgcn_s_setprio(0); }while(0)
#define VMC(n) asm volatile("s_waitcnt vmcnt(" #n ")" ::: "memory")

  // prologue: tile 0's 4 units in consumption order; allow 2 newest pending.
  STAGE_A(0, 0, 0); STAGE_B(0, 0, 0); STAGE_A(0, 0, 1); STAGE_B(0, 0, 1);
  VMC(4);
  __builtin_amdgcn_s_barrier();
  int cur = 0;
  for (int t=0; t<32; ++t){
    const bool pf = (t < 31);
    // ---- ph0: (mh0,kk0); stage A-mh0(t+1)
    LOAD_AF(0,0); LOAD_BF(bfA, 0);
    if (pf){ STAGE_A(cur^1, t+1, 0); VMC(4); } else VMC(2);
    PHASE_MFMA(0, bfA);
    // ---- ph1: (mh1,kk0); stage B-kk0(t+1)
    LOAD_AF(1,0);
    if (pf){ STAGE_B(cur^1, t+1, 0); VMC(4); } else VMC(0);
    PHASE_MFMA(1, bfA);
    // ---- ph2: (mh0,kk1); stage A-mh1(t+1)  [no vmcnt point]
    LOAD_AF(0,1); LOAD_BF(bfB, 1);
    if (pf) STAGE_A(cur^1, t+1, 1);
    PHASE_MFMA(0, bfB);
    // ---- ph3: (mh1,kk1); stage B-kk1(t+1)
    LOAD_AF(1,1);
    if (pf){ STAGE_B(cur^1, t+1, 1); VMC(4); }
    PHASE_MFMA(1, bfB);
    cur ^= 1;
  }
#undef STAGE_A
#undef STAGE_B
#undef LOAD_AF
#undef LOAD_BF
#undef PHASE_MFMA
#undef VMC

  if constexpr (EPI==3){
    float* O = (float*)O0;
    #pragma unroll
    for (int mh=0; mh<2; ++mh)
      #pragma unroll
      for (int fi=0; fi<4; ++fi){
        const int m0 = bm + wm*128 + mh*64 + fi*16 + rgrp*4;
        #pragma unroll
        for (int fj=0; fj<4; ++fj){
          const int n = bn + wn*64 + fj*16 + cidx;
          #pragma unroll
          for (int r=0; r<4; ++r)
            O[(size_t)(m0+r)*2048 + n] = acc[mh][fi][fj][r];
        }
      }
  } else {
    const int seg = bn>>11;                  // block-uniform: 0=Q, 1=K, 2=V
    if (seg==2){
      u16* O = (u16*)O2;                     // v_t [bh][128][2048]
      #pragma unroll
      for (int mh=0; mh<2; ++mh)
        #pragma unroll
        for (int fi=0; fi<4; ++fi){
          const int m0 = bm + wm*128 + mh*64 + fi*16 + rgrp*4;
          const int b = m0>>11, s0 = m0&2047;
          #pragma unroll
          for (int fj=0; fj<4; ++fj){
            const int nl = (bn + wn*64 + fj*16 + cidx) & 2047;
            const int h = nl>>7, d = nl&127;
            u16x4 pk = { f2bf(acc[mh][fi][fj][0]), f2bf(acc[mh][fi][fj][1]),
                         f2bf(acc[mh][fi][fj][2]), f2bf(acc[mh][fi][fj][3]) };
            *(u16x4*)(O + ((size_t)((b*16+h)*128 + d)*2048 + s0)) = pk;
          }
        }
    } else {
      u16* O = seg ? (u16*)O1 : (u16*)O0;    // [bh][2048][128]
      const float qs = seg ? 1.0f : 0.08838834764831845f;  // 1/sqrt(128) on Q
      #pragma unroll
      for (int fj=0; fj<4; ++fj){
        const int nl = (bn + wn*64 + fj*16 + cidx) & 2047;
        const int h = nl>>7, d = nl&127, f = (nl&127)>>1;
        #pragma unroll
        for (int mh=0; mh<2; ++mh)
          #pragma unroll
          for (int fi=0; fi<4; ++fi){
            #pragma unroll
            for (int r=0; r<4; ++r){
              const int m = bm + wm*128 + mh*64 + fi*16 + rgrp*4 + r;
              const int b = m>>11, s = m&2047;
              float v = acc[mh][fi][fj][r];
              float p = __shfl_xor(v, 1, 64);  // RoPE partner: d^1 lives in lane^1
              float cv = ct[s*64+f], sv = stab[s*64+f];
              float o = (d&1) ? (p*sv + v*cv) : (v*cv - p*sv);
              o *= qs;
              O[(size_t)(b*16+h)*262144 + (size_t)s*128 + d] = f2bf(o);
            }
          }
      }
    }
  }
}

// ---------------------------------------------------------------- flash attn
// 1-D grid, 1024 blocks, LPT order: qt = 15 - bid/64, bh = bid%64.
// QBLK=128: wave w owns q rows [qt*128 + w*32, +32) = 2 M-fragments.
// Swapped QK^T: stt[m][t] = mfma(K_frag, Q_frag) -> S[key][q], q = lane&15.
// Softmax: in-lane 16-value reduce + shfl_xor(16,32). P packed as u16x4 ->
// 8 ds_write_b64/wave. K/V double-buffered, XOR-swizzled (rule 21), counted
// vmcnt(8) + raw s_barrier (T3/T4), setprio (T5), defer-max (T13).
__global__ __launch_bounds__(256,2) void k_attn(
  const bf16_t* __restrict__ Q, const bf16_t* __restrict__ K,
  const bf16_t* __restrict__ Vt, u16* __restrict__ Mg)
{
  __shared__ char kl[2][16384];
  __shared__ char vl[2][16384];
  __shared__ char pl[4][4096];                // per-wave P: 32 q-rows x 128B, XOR-swz
  const int tid=threadIdx.x, wave=tid>>6, lane=tid&63;
  const int rgrp=lane>>4, cidx=lane&15;
  const int bid=blockIdx.x;
  const int qt = 15 - (bid>>6);
  const int bh = bid & 63;
  const int qbase = qt*128;
  const int last = 2*qt + 1;                  // inclusive last k-tile

  bf16x8 qf[2][4];                            // B-operand: lane <- q row m*16+cidx
  #pragma unroll
  for (int m=0;m<2;++m){
    const bf16_t* qp = Q + ((size_t)bh*2048 + qbase + wave*32 + m*16 + cidx)*128 + rgrp*8;
    #pragma unroll
    for (int ds=0; ds<4; ++ds) qf[m][ds] = *(const bf16x8*)(qp + ds*32);
  }
  f32x4 oacc[2][8] = {};
  float mrow[2] = {-1e30f,-1e30f};
  float lrow[2] = {0.f,0.f};

  const char* Kg = (const char*)K  + (size_t)bh*524288;
  const char* Vg = (const char*)Vt + (size_t)bh*524288;
  char* pw = pl[wave];
  const int L0 = tid*16;
  const int qrow0 = qbase + wave*32 + cidx;   // q-row of frag m: qrow0 + m*16

  #define STAGE(buf, kt_) do{                                                  \
    _Pragma("unroll")                                                          \
    for (int i_=0;i_<4;++i_){                                                  \
      int L_ = i_*4096 + L0;                                                   \
      int row_ = L_>>8;                                                        \
      int in_ = (L_&255) ^ ((row_&7)<<4);                                      \
      GLL16(Kg + (size_t)((kt_)*64+row_)*256 + in_, &kl[buf][i_*4096 + wave*1024]); \
    }                                                                          \
    _Pragma("unroll")                                                          \
    for (int i_=0;i_<4;++i_){                                                  \
      int L_ = i_*4096 + L0;                                                   \
      int d_ = L_>>7;                                                          \
      int in_ = (L_&127) ^ ((d_&7)<<4);                                        \
      GLL16(Vg + (size_t)d_*4096 + (kt_)*128 + in_, &vl[buf][i_*4096 + wave*1024]); \
    }                                                                          \
  }while(0)

  STAGE(0, 0);
  int cur = 0;
  for (int kt=0; kt<=last; ++kt){
    const bool pf = (kt < last);
    if (pf) STAGE(cur^1, kt+1);               // 8 more GLLs in flight
    if (pf) asm volatile("s_waitcnt vmcnt(8)" ::: "memory");
    else    asm volatile("s_waitcnt vmcnt(0)" ::: "memory");
    __builtin_amdgcn_s_barrier();             // buf[cur] ready everywhere

    // ---- S^T = K Q^T : stt[m][t][r] = S[key = kt*64+t*16+rgrp*4+r][q = qrow0+m*16]
    f32x4 stt[2][4];
    #pragma unroll
    for (int m=0;m<2;++m)
      #pragma unroll
      for (int t=0;t<4;++t) stt[m][t] = (f32x4){0.f,0.f,0.f,0.f};
    __builtin_amdgcn_s_setprio(1);
    #pragma unroll
    for (int t=0;t<4;++t){
      const int krow = t*16 + cidx;           // A-operand: lane <- K row krow
      #pragma unroll
      for (int ds=0; ds<4; ++ds){
        const int off = (krow*256 + ds*64 + rgrp*16) ^ ((krow&7)<<4);
        bf16x8 kf = *(const bf16x8*)(&kl[cur][off]);
        stt[0][t] = mfma16(kf, qf[0][ds], stt[0][t]);
        stt[1][t] = mfma16(kf, qf[1][ds], stt[1][t]);
      }
    }
    __builtin_amdgcn_s_setprio(0);

    // ---- causal mask (only the last two tiles of this q-block can clip)
    if (kt >= 2*qt){
      #pragma unroll
      for (int m=0;m<2;++m){
        const int q = qrow0 + m*16;
        #pragma unroll
        for (int t=0;t<4;++t){
          #pragma unroll
          for (int r=0;r<4;++r){
            const int key = kt*64 + t*16 + rgrp*4 + r;
            if (key > q) stt[m][t][r] = -1e30f;
          }
        }
      }
    }

    // ---- online softmax, in-lane per q-row
    #pragma unroll
    for (int m=0;m<2;++m){
      float vm = stt[m][0][0];
      #pragma unroll
      for (int t=0;t<4;++t)
        #pragma unroll
        for (int r=0;r<4;++r) vm = fmaxf(vm, stt[m][t][r]);
      vm = fmaxf(vm, __shfl_xor(vm, 16, 64));
      vm = fmaxf(vm, __shfl_xor(vm, 32, 64));
      if (!__all(vm <= mrow[m] + 8.f)){       // T13: rescale only on real growth
        float mn = fmaxf(mrow[m], vm);
        float c = __expf(mrow[m]-mn);
        mrow[m]=mn; lrow[m]*=c;
        float cr0 = __shfl(c, rgrp*4+0, 64), cr1 = __shfl(c, rgrp*4+1, 64);
        float cr2 = __shfl(c, rgrp*4+2, 64), cr3 = __shfl(c, rgrp*4+3, 64);
        #pragma unroll
        for (int d=0;d<8;++d){
          oacc[m][d][0]*=cr0; oacc[m][d][1]*=cr1;
          oacc[m][d][2]*=cr2; oacc[m][d][3]*=cr3;
        }
      }
      float lt = 0.f;
      #pragma unroll
      for (int t=0;t<4;++t)
        #pragma unroll
        for (int r=0;r<4;++r){
          float p = __expf(stt[m][t][r]-mrow[m]);
          stt[m][t][r]=p; lt+=p;
        }
      lt += __shfl_xor(lt, 16, 64);
      lt += __shfl_xor(lt, 32, 64);
      lrow[m] += lt;
    }

    // ---- P pack -> per-wave LDS (XOR-swz), 4 consecutive keys per write
    #pragma unroll
    for (int m=0;m<2;++m){
      const int prow = m*16 + cidx;
      char* base = pw + prow*128;
      const int swz = (prow&7)<<4;
      #pragma unroll
      for (int t=0;t<4;++t){
        u16x4 pk = { f2bf(stt[m][t][0]), f2bf(stt[m][t][1]), f2bf(stt[m][t][2]), f2bf(stt[m][t][3]) };
        *(u16x4*)(base + ((t*32 + rgrp*8) ^ swz)) = pk;
      }
    }
    asm volatile("s_waitcnt lgkmcnt(0)" ::: "memory");
    __builtin_amdgcn_sched_barrier(0);

    // ---- O += P V^T
    __builtin_amdgcn_s_setprio(1);
    #pragma unroll
    for (int ks=0; ks<2; ++ks){
      const int swzc = (cidx&7)<<4;
      bf16x8 pa0 = *(const bf16x8*)(pw + (     cidx)*128 + ((ks*64 + rgrp*16) ^ swzc));
      bf16x8 pa1 = *(const bf16x8*)(pw + (16 + cidx)*128 + ((ks*64 + rgrp*16) ^ swzc));
      #pragma unroll
      for (int dsub=0; dsub<8; ++dsub){
        const int d = dsub*16 + cidx;
        const int off = (d*128 + ks*64 + rgrp*16) ^ ((d&7)<<4);
        bf16x8 vf = *(const bf16x8*)(&vl[cur][off]);
        oacc[0][dsub] = mfma16(pa0, vf, oacc[0][dsub]);
        oacc[1][dsub] = mfma16(pa1, vf, oacc[1][dsub]);
      }
    }
    __builtin_amdgcn_s_setprio(0);
    __builtin_amdgcn_s_barrier();             // all reads of buf[cur] done
    cur ^= 1;
  }
  #undef STAGE

  const int b = bh>>4, h = bh&15;
  #pragma unroll
  for (int m=0;m<2;++m){
    float linv = 1.f/lrow[m];
    float ir[4];
    #pragma unroll
    for (int r=0;r<4;++r) ir[r] = __shfl(linv, rgrp*4+r, 64);
    #pragma unroll
    for (int dsub=0;dsub<8;++dsub){
      const int col = h*128 + dsub*16 + cidx;
      #pragma unroll
      for (int r=0;r<4;++r){
        const int srow = qbase + wave*32 + m*16 + rgrp*4 + r;
        Mg[((size_t)b*2048 + srow)*2048 + col] = f2bf(oacc[m][dsub][r]*ir[r]);
      }
    }
  }
}

// ---------------------------------------------------------------- launch
extern "C" void kernel_launch(void* const* d_in, const int* in_sizes, int n_in,
                              void* d_out, int out_size, void* d_ws, size_t ws_size,
                              hipStream_t stream)
{
  (void)in_sizes; (void)n_in; (void)out_size; (void)ws_size;
  const float* x  = (const float*)d_in[0];
  const int*   tp = (const int*)d_in[1];
  const float* Wq = (const float*)d_in[2];
  const float* Wk = (const float*)d_in[3];
  const float* Wv = (const float*)d_in[4];
  const float* Wo = (const float*)d_in[5];

  char* ws = (char*)d_ws;
  bf16_t* xb  = (bf16_t*)(ws);                 // 33.5MB, reused as merged later
  bf16_t* wqb = (bf16_t*)(ws + 33554432);      // wq|wk|wv|wo contiguous
  bf16_t* wob = (bf16_t*)(ws + 58720256);
  bf16_t* vt  = (bf16_t*)(ws + 67108864);      // 33.5MB
  float*  ct  = (float*) (ws + 100663296);     // 512KB
  float*  stb = (float*) (ws + 101187584);     // 512KB  (end ~97MB)
  bf16_t* qr  = (bf16_t*)d_out;                // q_rope in d_out (dead before final GEMM)
  bf16_t* kr  = (bf16_t*)((char*)d_out + 33554432);
  bf16_t* mg  = xb;                            // merged reuses xb

  k_prep<<<2048,256,0,stream>>>(x, Wq, Wk, Wv, Wo, tp,
                                (u16*)xb, (u16*)wqb, ct, stb);

  k_gemm<4><<<768,512,0,stream>>>(xb, wqb, qr, kr, vt, ct, stb);
  k_attn<<<1024,256,0,stream>>>(qr, kr, vt, (u16*)mg);
  k_gemm<3><<<256,512,0,stream>>>(mg, wob, d_out, nullptr, nullptr, nullptr, nullptr);
}